// Round 1
// baseline (134.337 us; speedup 1.0000x reference)
//
#include <hip/hip_runtime.h>
#include <math.h>

typedef unsigned long long u64;
typedef unsigned int u32;

#define NB 256       // batch
#define NQ 1000      // queries
#define NC 80        // classes
#define QC 80000     // NQ*NC per row
#define TOPK 300
#define CAP 2048     // candidate capacity (power of 2, = bitonic sort size)
#define NTHREADS 1024

// One block per batch row. Collect candidates with logit > T (T=2.0 yields
// ~1820 +/- 42 of 80000 for N(0,1) data; retry loop adjusts T if a row ever
// falls outside [300, 2048]). Sort candidates descending by
// (logit_bits, inverted index) -- lower index wins exact ties, matching
// jax.lax.top_k. Emit top 300: labels, xyxy boxes, sigmoid scores.
__global__ __launch_bounds__(NTHREADS) void postproc_kernel(
    const float* __restrict__ logits,
    const float4* __restrict__ boxes,
    float* __restrict__ out) {
  const int row = blockIdx.x;
  const int tid = threadIdx.x;

  __shared__ u64 s_keys[CAP];
  __shared__ int s_cnt;

  const float4* lp = (const float4*)logits + (size_t)row * (QC / 4);

  float T = 2.0f;
  int cnt = 0;
  for (int attempt = 0; attempt < 24; ++attempt) {
    __syncthreads();
    if (tid == 0) s_cnt = 0;
    __syncthreads();
    for (int i = tid; i < QC / 4; i += NTHREADS) {
      float4 v = lp[i];
      float xs[4] = {v.x, v.y, v.z, v.w};
#pragma unroll
      for (int c = 0; c < 4; ++c) {
        float x = xs[c];
        if (x > T) {
          int pos = atomicAdd(&s_cnt, 1);
          if (pos < CAP) {
            u32 bits = __float_as_uint(x);        // x > T >= ~0 -> positive: bits monotone
            u32 idx = (u32)(4 * i + c);           // flat index in [0, 80000)
            s_keys[pos] = ((u64)bits << 32) | (u64)(0xFFFFFFFFu - idx);
          }
        }
      }
    }
    __syncthreads();
    cnt = s_cnt;
    if (cnt >= TOPK && cnt <= CAP) break;
    T = (cnt < TOPK) ? (T - 0.9f) : (T + 0.45f);
  }
  if (cnt > CAP) cnt = CAP;

  // pad to CAP with zero keys (sort last under descending order)
  for (int i = cnt + tid; i < CAP; i += NTHREADS) s_keys[i] = 0ull;
  __syncthreads();

  // bitonic sort, descending, CAP elements, CAP/2 = 1024 compare-exchanges
  // per half-stage = exactly one per thread.
  for (int size = 2; size <= CAP; size <<= 1) {
    for (int stride = size >> 1; stride > 0; stride >>= 1) {
      int i = tid;
      int lo = 2 * i - (i & (stride - 1));
      int hi = lo + stride;
      u64 a = s_keys[lo];
      u64 b = s_keys[hi];
      bool desc = (lo & size) == 0;
      bool sw = desc ? (a < b) : (a > b);
      if (sw) {
        s_keys[lo] = b;
        s_keys[hi] = a;
      }
      __syncthreads();
    }
  }

  // epilogue: threads 0..299 emit one result each
  if (tid < TOPK) {
    const int k = tid;
    float* labels_out = out;                       // [NB, TOPK]
    float* boxes_out = out + NB * TOPK;            // [NB, TOPK, 4]
    float* scores_out = out + NB * TOPK * 5;       // [NB, TOPK]

    float lab = 0.0f, score = 0.0f;
    float4 bo = make_float4(0.0f, 0.0f, 0.0f, 0.0f);
    if (k < cnt) {
      u64 key = s_keys[k];
      u32 idx = 0xFFFFFFFFu - (u32)(key & 0xFFFFFFFFull);
      float x = __uint_as_float((u32)(key >> 32));
      int q = (int)(idx / NC);
      int c = (int)(idx - (u32)q * NC);
      lab = (float)c;
      // correctly-rounded f32 sigmoid via double
      score = (float)(1.0 / (1.0 + exp(-(double)x)));
      float4 bb = boxes[(size_t)row * NQ + q];
      float hw = 0.5f * bb.z, hh = 0.5f * bb.w;
      bo.x = bb.x - hw;
      bo.y = bb.y - hh;
      bo.z = bb.x + hw;
      bo.w = bb.y + hh;
    }
    labels_out[row * TOPK + k] = lab;
    scores_out[row * TOPK + k] = score;
    ((float4*)boxes_out)[row * TOPK + k] = bo;
  }
}

extern "C" void kernel_launch(void* const* d_in, const int* in_sizes, int n_in,
                              void* d_out, int out_size, void* d_ws, size_t ws_size,
                              hipStream_t stream) {
  const float* logits = (const float*)d_in[0];
  const float4* boxes = (const float4*)d_in[1];
  float* out = (float*)d_out;
  postproc_kernel<<<NB, NTHREADS, 0, stream>>>(logits, boxes, out);
}